// Round 4
// baseline (384.288 us; speedup 1.0000x reference)
//
#include <hip/hip_runtime.h>

#define FDIM 128
#define LN_EPS 1e-5f
#define CAP 64          // padded slots per node; P(deg>64) ~ 1e-18 for Poisson(16)

typedef short short8 __attribute__((ext_vector_type(8)));
typedef float f32x4 __attribute__((ext_vector_type(4)));

__device__ __forceinline__ ushort f2bf(float f) {
    uint u = __float_as_uint(f);
    u += 0x7fff + ((u >> 16) & 1);      // RNE
    return (ushort)(u >> 16);
}
__device__ __forceinline__ float bflo(uint u) { return __uint_as_float(u << 16); }
__device__ __forceinline__ float bfhi(uint u) { return __uint_as_float(u & 0xffff0000u); }

// ---------------- bucket build ----------------
__global__ void k_zero(int* __restrict__ cnt, int n) {
    int i = blockIdx.x * 256 + threadIdx.x;
    if (i < n) cnt[i] = 0;
}

__global__ void k_build(const int* __restrict__ src, const int* __restrict__ dst,
                        int* __restrict__ cnt, uint* __restrict__ colp, int E) {
    int e = blockIdx.x * 256 + threadIdx.x;
    if (e < E) {
        int d = dst[e];
        int slot = atomicAdd(&cnt[d], 1);
        if (slot < CAP) colp[(size_t)d * CAP + slot] = (uint)src[e];
    }
}

// ---------------- W[128,128] fp32 -> W^T bf16 (both weights, one launch) ----------------
__global__ void k_wt2(const float* __restrict__ W1, const float* __restrict__ W2,
                      ushort* __restrict__ WT1, ushort* __restrict__ WT2) {
    int b = blockIdx.x, k = threadIdx.x;
    if (b < 128) WT1[b * 128 + k] = f2bf(W1[k * 128 + b]);
    else         WT2[(b - 128) * 128 + k] = f2bf(W2[k * 128 + (b - 128)]);
}

// ---------------- MFMA GEMM: H_bf16[N,128] = X[N,128] @ WT^T ----------------
// mfma(a=W-col frag, b=X-row frag) -> lane holds row r=lane&15,
// cols (lane>>4)*4+reg (consecutive) => 8B stores.
template <bool F32IN>
__global__ __launch_bounds__(256) void k_gemm(const void* __restrict__ Xin,
                                              const ushort* __restrict__ WT,
                                              ushort* __restrict__ H, int N) {
    int w = threadIdx.x >> 6, lane = threadIdx.x & 63;
    int cl = lane & 15, kq = lane >> 4;
    int r = blockIdx.x * 64 + w * 16 + cl;
    int rc = min(r, N - 1);
    const short8* W8 = (const short8*)WT;

    short8 b0, b1, b2, b3;   // X row rc, k-chunks kt*32 + kq*8 .. +7
    if constexpr (F32IN) {
        const float4* X4 = (const float4*)((const float*)Xin + (size_t)rc * 128);
#pragma unroll
        for (int kt = 0; kt < 4; ++kt) {
            float4 v0 = X4[kt * 8 + kq * 2];
            float4 v1 = X4[kt * 8 + kq * 2 + 1];
            short8 o;
            o[0] = (short)f2bf(v0.x); o[1] = (short)f2bf(v0.y);
            o[2] = (short)f2bf(v0.z); o[3] = (short)f2bf(v0.w);
            o[4] = (short)f2bf(v1.x); o[5] = (short)f2bf(v1.y);
            o[6] = (short)f2bf(v1.z); o[7] = (short)f2bf(v1.w);
            if (kt == 0) b0 = o; else if (kt == 1) b1 = o; else if (kt == 2) b2 = o; else b3 = o;
        }
    } else {
        const short8* X8 = (const short8*)Xin;
        b0 = X8[(size_t)rc * 16 + 0 * 4 + kq];
        b1 = X8[(size_t)rc * 16 + 1 * 4 + kq];
        b2 = X8[(size_t)rc * 16 + 2 * 4 + kq];
        b3 = X8[(size_t)rc * 16 + 3 * 4 + kq];
    }

    bool ok = r < N;
#pragma unroll
    for (int nt = 0; nt < 8; ++nt) {
        int c = nt * 16 + cl;                      // WT row = W col
        f32x4 acc = {0.f, 0.f, 0.f, 0.f};
        acc = __builtin_amdgcn_mfma_f32_16x16x32_bf16(W8[c * 16 + 0 * 4 + kq], b0, acc, 0, 0, 0);
        acc = __builtin_amdgcn_mfma_f32_16x16x32_bf16(W8[c * 16 + 1 * 4 + kq], b1, acc, 0, 0, 0);
        acc = __builtin_amdgcn_mfma_f32_16x16x32_bf16(W8[c * 16 + 2 * 4 + kq], b2, acc, 0, 0, 0);
        acc = __builtin_amdgcn_mfma_f32_16x16x32_bf16(W8[c * 16 + 3 * 4 + kq], b3, acc, 0, 0, 0);
        if (ok) {
            ushort4 o;
            o.x = f2bf(acc[0]); o.y = f2bf(acc[1]);
            o.z = f2bf(acc[2]); o.w = f2bf(acc[3]);
            *(ushort4*)(H + (size_t)r * 128 + nt * 16 + kq * 4) = o;
        }
    }
}

// ------- aggregate(bf16 h) + bias + ReLU + LN; 2 nodes/wave, uint2 gathers -------
// edge lists come from padded buckets colp[node*CAP + i], i < cnt[node];
// dinv computed inline as rsqrt(cnt+1).
__global__ __launch_bounds__(256) void k_agg(const uint2* __restrict__ H2,
                                             const int* __restrict__ cnt,
                                             const uint* __restrict__ colp,
                                             const float* __restrict__ bias,
                                             const float* __restrict__ gamma,
                                             const float* __restrict__ beta,
                                             float* __restrict__ outf,
                                             uint2* __restrict__ outb,
                                             int N) {
    int wave = threadIdx.x >> 6;
    int lane = threadIdx.x & 63;
    int half = lane >> 5;
    int l = lane & 31;                     // covers features 4l..4l+3
    int node = blockIdx.x * 8 + wave * 2 + half;
    bool valid = node < N;
    int nodec = valid ? node : N - 1;

    int deg = cnt[nodec];
    float di = rsqrtf((float)deg + 1.0f);
    uint2 hs = H2[(size_t)nodec * 32 + l];
    float ax = di * bflo(hs.x), ay = di * bfhi(hs.x);
    float az = di * bflo(hs.y), aw = di * bfhi(hs.y);

    const uint* cp = colp + (size_t)nodec * CAP;
    int mx = max(deg, __shfl_xor(deg, 32));      // pair max (<= CAP)

#define EDGE(ii, sv)                                                        \
    {                                                                       \
        bool act = (ii) < deg;                                              \
        int s = act ? (int)(sv) : 0;                                        \
        float ww = act ? rsqrtf((float)cnt[s] + 1.0f) : 0.f;                \
        uint2 u = H2[(size_t)s * 32 + l];                                   \
        ax = fmaf(ww, bflo(u.x), ax); ay = fmaf(ww, bfhi(u.x), ay);         \
        az = fmaf(ww, bflo(u.y), az); aw = fmaf(ww, bfhi(u.y), aw);         \
    }

    for (int i = 0; i < mx; i += 4) {
        uint4 c4 = *(const uint4*)(cp + i);      // broadcast, padded-safe
        EDGE(i + 0, c4.x)
        EDGE(i + 1, c4.y)
        EDGE(i + 2, c4.z)
        EDGE(i + 3, c4.w)
    }
#undef EDGE

    float4 bb = ((const float4*)bias)[l];
    float a0 = fmaxf(fmaf(ax, di, bb.x), 0.f);
    float a1 = fmaxf(fmaf(ay, di, bb.y), 0.f);
    float a2 = fmaxf(fmaf(az, di, bb.z), 0.f);
    float a3 = fmaxf(fmaf(aw, di, bb.w), 0.f);

    float s1 = a0 + a1 + a2 + a3;
    float s2 = a0 * a0 + a1 * a1 + a2 * a2 + a3 * a3;
#pragma unroll
    for (int off = 16; off >= 1; off >>= 1) {     // width-32 butterfly
        s1 += __shfl_xor(s1, off);
        s2 += __shfl_xor(s2, off);
    }
    float mu = s1 * (1.f / 128.f);
    float var = s2 * (1.f / 128.f) - mu * mu;
    float rs = rsqrtf(var + LN_EPS);

    float4 g = ((const float4*)gamma)[l];
    float4 be = ((const float4*)beta)[l];
    float o0 = (a0 - mu) * rs * g.x + be.x;
    float o1 = (a1 - mu) * rs * g.y + be.y;
    float o2 = (a2 - mu) * rs * g.z + be.z;
    float o3 = (a3 - mu) * rs * g.w + be.w;

    if (!valid) return;
    if (outf) {
        ((float4*)outf)[(size_t)node * 32 + l] = make_float4(o0, o1, o2, o3);
    } else {
        uint2 o;
        o.x = (uint)f2bf(o0) | ((uint)f2bf(o1) << 16);
        o.y = (uint)f2bf(o2) | ((uint)f2bf(o3) << 16);
        outb[(size_t)node * 32 + l] = o;
    }
}

// ---------------- launch ----------------
extern "C" void kernel_launch(void* const* d_in, const int* in_sizes, int n_in,
                              void* d_out, int out_size, void* d_ws, size_t ws_size,
                              hipStream_t stream) {
    const float* x  = (const float*)d_in[0];
    const int*   ei = (const int*)d_in[1];
    const float* W1 = (const float*)d_in[2];
    const float* b1 = (const float*)d_in[3];
    const float* W2 = (const float*)d_in[4];
    const float* b2 = (const float*)d_in[5];
    const float* g1 = (const float*)d_in[6];
    const float* be1 = (const float*)d_in[7];
    const float* g2 = (const float*)d_in[8];
    const float* be2 = (const float*)d_in[9];

    int N = in_sizes[0] / FDIM;
    int E = in_sizes[1] / 2;
    const int* srcp = ei;
    const int* dstp = ei + E;
    float* out = (float*)d_out;

    char* w = (char*)d_ws;
    size_t off = 0;
    auto take = [&](size_t bytes) {
        void* p = w + off;
        off = (off + bytes + 255) & ~(size_t)255;
        return p;
    };
    ushort* hb  = (ushort*)take((size_t)N * FDIM * sizeof(ushort));   // gemm out bf16
    ushort* WT1 = (ushort*)take(128 * 128 * sizeof(ushort));
    ushort* WT2 = (ushort*)take(128 * 128 * sizeof(ushort));
    int* cnt    = (int*)take((size_t)N * sizeof(int));
    uint* colp  = (uint*)take((size_t)N * CAP * sizeof(uint));        // padded buckets
    (void)ws_size;

    // bucket build (shared by both layers)
    k_zero<<<(N + 255) / 256, 256, 0, stream>>>(cnt, N);
    k_build<<<(E + 255) / 256, 256, 0, stream>>>(srcp, dstp, cnt, colp, E);

    // weights -> W^T bf16
    k_wt2<<<256, 128, 0, stream>>>(W1, W2, WT1, WT2);

    // layer 1: gemm (fp32 in, convert fused) -> agg (bf16 out into d_out front)
    k_gemm<true><<<(N + 63) / 64, 256, 0, stream>>>(x, WT1, hb, N);
    k_agg<<<(N + 7) / 8, 256, 0, stream>>>((const uint2*)hb, cnt, colp,
                                           b1, g1, be1, nullptr, (uint2*)d_out, N);
    // layer 2: gemm reads bf16 from d_out, agg writes final fp32 d_out
    k_gemm<false><<<(N + 63) / 64, 256, 0, stream>>>(d_out, WT2, hb, N);
    k_agg<<<(N + 7) / 8, 256, 0, stream>>>((const uint2*)hb, cnt, colp,
                                           b2, g2, be2, out, nullptr, N);
}

// Round 5
// 325.712 us; speedup vs baseline: 1.1798x; 1.1798x over previous
//
#include <hip/hip_runtime.h>

#define FDIM 128
#define LN_EPS 1e-5f

typedef short short8 __attribute__((ext_vector_type(8)));
typedef float f32x4 __attribute__((ext_vector_type(4)));

__device__ __forceinline__ ushort f2bf(float f) {
    uint u = __float_as_uint(f);
    u += 0x7fff + ((u >> 16) & 1);      // RNE
    return (ushort)(u >> 16);
}
__device__ __forceinline__ float bflo(uint u) { return __uint_as_float(u << 16); }
__device__ __forceinline__ float bfhi(uint u) { return __uint_as_float(u & 0xffff0000u); }

// ---------------- CSR build (exact; 6.4MB col region -> L2-merged scatter) ----------------
__global__ void k_zero(int* __restrict__ cnt, int n) {
    int i = blockIdx.x * 256 + threadIdx.x;
    if (i < n) cnt[i] = 0;
}

__global__ void k_count(const int* __restrict__ dst, int* __restrict__ cnt,
                        int* __restrict__ pos, int E) {
    int e = blockIdx.x * 256 + threadIdx.x;
    if (e < E) pos[e] = atomicAdd(&cnt[dst[e]], 1);
}

__global__ __launch_bounds__(1024) void k_scan_block(const int* __restrict__ cnt,
                                                     int* __restrict__ rowptr,
                                                     int* __restrict__ partial, int N) {
    __shared__ int s[1024];
    int t = threadIdx.x;
    int i = blockIdx.x * 1024 + t;
    int v = (i < N) ? cnt[i] : 0;
    s[t] = v;
    __syncthreads();
    for (int off = 1; off < 1024; off <<= 1) {
        int u = (t >= off) ? s[t - off] : 0;
        __syncthreads();
        s[t] += u;
        __syncthreads();
    }
    if (i < N) rowptr[i] = s[t] - v;
    if (t == 1023) partial[blockIdx.x] = s[1023];
}

__global__ __launch_bounds__(1024) void k_scan_partial(int* __restrict__ partial, int NB) {
    __shared__ int s[1024];
    int t = threadIdx.x;
    int v = (t < NB) ? partial[t] : 0;
    s[t] = v;
    __syncthreads();
    for (int off = 1; off < 1024; off <<= 1) {
        int u = (t >= off) ? s[t - off] : 0;
        __syncthreads();
        s[t] += u;
        __syncthreads();
    }
    if (t < NB) partial[t] = s[t] - v;
}

__global__ void k_finalize(int* __restrict__ rowptr, const int* __restrict__ partial,
                           const int* __restrict__ cnt, float* __restrict__ dinv,
                           int N, int E) {
    int i = blockIdx.x * 256 + threadIdx.x;
    if (i < N) {
        rowptr[i] += partial[i >> 10];
        dinv[i] = rsqrtf((float)cnt[i] + 1.0f);
    }
    if (i == 0) rowptr[N] = E;
}

__global__ void k_fill(const int* __restrict__ src, const int* __restrict__ dst,
                       const int* __restrict__ rowptr, const int* __restrict__ pos,
                       int* __restrict__ col, int E) {
    int e = blockIdx.x * 256 + threadIdx.x;
    if (e < E) col[rowptr[dst[e]] + pos[e]] = src[e];
    if (e < 8) col[E + e] = 0;           // slack so agg's unroll-8 tail reads valid ids
}

// ---------------- W[128,128] fp32 -> W^T bf16 (both weights, one launch) ----------------
__global__ void k_wt2(const float* __restrict__ W1, const float* __restrict__ W2,
                      ushort* __restrict__ WT1, ushort* __restrict__ WT2) {
    int b = blockIdx.x, k = threadIdx.x;
    if (b < 128) WT1[b * 128 + k] = f2bf(W1[k * 128 + b]);
    else         WT2[(b - 128) * 128 + k] = f2bf(W2[k * 128 + (b - 128)]);
}

// ---------------- MFMA GEMM: H_bf16[N,128] = X[N,128] @ WT^T ----------------
// X staged through LDS (coalesced global reads; XOR-swizzled b128 frag reads).
// mfma(a=W-col frag, b=X-row frag): lane holds out row r=lane&15,
// cols (lane>>4)*4+reg (consecutive) => 8B stores.
template <bool F32IN>
__global__ __launch_bounds__(256) void k_gemm(const void* __restrict__ Xin,
                                              const ushort* __restrict__ WT,
                                              ushort* __restrict__ H, int N) {
    __shared__ ushort sX[64 * 128];      // 16 KB, bf16, swizzled rows of 256B
    char* sXb = (char*)sX;

    int t = threadIdx.x;
    int w = t >> 6, lane = t & 63;
    int cl = lane & 15, kq = lane >> 4;
    int base = blockIdx.x * 64;

    // ---- stage X tile (rows base..base+63) ----
    if constexpr (F32IN) {
        const float4* X4 = (const float4*)Xin;
        size_t lim = (size_t)N * 32 - 1;
#pragma unroll
        for (int k = 0; k < 8; ++k) {
            int idx = t + k * 256;                    // 0..2047 = 64 rows x 32 f4
            size_t gi = (size_t)base * 32 + idx;
            float4 v = X4[gi < lim ? gi : lim];
            ushort4 o;
            o.x = f2bf(v.x); o.y = f2bf(v.y); o.z = f2bf(v.z); o.w = f2bf(v.w);
            int row = idx >> 5, b8 = (idx & 31) * 8;  // byte col within 256B row
            *(ushort4*)(sXb + row * 256 + (b8 ^ ((row & 7) << 4))) = o;
        }
    } else {
        const short8* X8 = (const short8*)Xin;
        size_t lim = (size_t)N * 16 - 1;
#pragma unroll
        for (int k = 0; k < 4; ++k) {
            int idx = t + k * 256;                    // 0..1023 = 64 rows x 16 s8
            size_t gi = (size_t)base * 16 + idx;
            short8 v = X8[gi < lim ? gi : lim];
            int row = idx >> 4, b16 = (idx & 15) * 16;
            *(short8*)(sXb + row * 256 + (b16 ^ ((row & 7) << 4))) = v;
        }
    }
    __syncthreads();

    // ---- fragments from LDS ----
    int rl = w * 16 + cl;                              // local row 0..63
    short8 b0, b1, b2, b3;
#pragma unroll
    for (int kt = 0; kt < 4; ++kt) {
        short8 v = *(const short8*)(sXb + rl * 256 + ((kt * 64 + kq * 16) ^ ((rl & 7) << 4)));
        if (kt == 0) b0 = v; else if (kt == 1) b1 = v; else if (kt == 2) b2 = v; else b3 = v;
    }

    const short8* W8 = (const short8*)WT;
    int r = base + rl;
    bool ok = r < N;
#pragma unroll
    for (int nt = 0; nt < 8; ++nt) {
        int c = nt * 16 + cl;                          // WT row = W col
        f32x4 acc = {0.f, 0.f, 0.f, 0.f};
        acc = __builtin_amdgcn_mfma_f32_16x16x32_bf16(W8[c * 16 + 0 * 4 + kq], b0, acc, 0, 0, 0);
        acc = __builtin_amdgcn_mfma_f32_16x16x32_bf16(W8[c * 16 + 1 * 4 + kq], b1, acc, 0, 0, 0);
        acc = __builtin_amdgcn_mfma_f32_16x16x32_bf16(W8[c * 16 + 2 * 4 + kq], b2, acc, 0, 0, 0);
        acc = __builtin_amdgcn_mfma_f32_16x16x32_bf16(W8[c * 16 + 3 * 4 + kq], b3, acc, 0, 0, 0);
        if (ok) {
            ushort4 o;
            o.x = f2bf(acc[0]); o.y = f2bf(acc[1]);
            o.z = f2bf(acc[2]); o.w = f2bf(acc[3]);
            *(ushort4*)(H + (size_t)r * 128 + nt * 16 + kq * 4) = o;
        }
    }
}

// ------- aggregate(bf16 h) + bias + ReLU + LN; 1 node/wave, two-phase unroll-8 -------
__global__ __launch_bounds__(256) void k_agg(const uint* __restrict__ H,   // bf16x2
                                             const int* __restrict__ rowptr,
                                             const int* __restrict__ col,
                                             const float* __restrict__ dinv,
                                             const float* __restrict__ bias,
                                             const float* __restrict__ gamma,
                                             const float* __restrict__ beta,
                                             float* __restrict__ outf,
                                             uint* __restrict__ outb,
                                             int N) {
    int wave = threadIdx.x >> 6;
    int lane = threadIdx.x & 63;
    int node = blockIdx.x * 4 + wave;
    if (node >= N) return;

    float di = dinv[node];
    uint hs = H[(size_t)node * 64 + lane];
    float ax = di * bflo(hs);
    float ay = di * bfhi(hs);

    int beg = rowptr[node];
    int deg = rowptr[node + 1] - beg;
    const int* cp = col + beg;

    for (int i = 0; i < deg; i += 8) {
        // phase 1: 8 independent col loads (reads past deg hit slack/next rows - valid ids)
        int s0 = cp[i + 0], s1 = cp[i + 1], s2 = cp[i + 2], s3 = cp[i + 3];
        int s4 = cp[i + 4], s5 = cp[i + 5], s6 = cp[i + 6], s7 = cp[i + 7];
        // phase 2: 8 independent weight + row gathers
        float w0 = (i + 0 < deg) ? dinv[s0] : 0.f;
        float w1 = (i + 1 < deg) ? dinv[s1] : 0.f;
        float w2 = (i + 2 < deg) ? dinv[s2] : 0.f;
        float w3 = (i + 3 < deg) ? dinv[s3] : 0.f;
        float w4 = (i + 4 < deg) ? dinv[s4] : 0.f;
        float w5 = (i + 5 < deg) ? dinv[s5] : 0.f;
        float w6 = (i + 6 < deg) ? dinv[s6] : 0.f;
        float w7 = (i + 7 < deg) ? dinv[s7] : 0.f;
        uint u0 = H[(size_t)s0 * 64 + lane];
        uint u1 = H[(size_t)s1 * 64 + lane];
        uint u2 = H[(size_t)s2 * 64 + lane];
        uint u3 = H[(size_t)s3 * 64 + lane];
        uint u4 = H[(size_t)s4 * 64 + lane];
        uint u5 = H[(size_t)s5 * 64 + lane];
        uint u6 = H[(size_t)s6 * 64 + lane];
        uint u7 = H[(size_t)s7 * 64 + lane];
        ax = fmaf(w0, bflo(u0), ax); ay = fmaf(w0, bfhi(u0), ay);
        ax = fmaf(w1, bflo(u1), ax); ay = fmaf(w1, bfhi(u1), ay);
        ax = fmaf(w2, bflo(u2), ax); ay = fmaf(w2, bfhi(u2), ay);
        ax = fmaf(w3, bflo(u3), ax); ay = fmaf(w3, bfhi(u3), ay);
        ax = fmaf(w4, bflo(u4), ax); ay = fmaf(w4, bfhi(u4), ay);
        ax = fmaf(w5, bflo(u5), ax); ay = fmaf(w5, bfhi(u5), ay);
        ax = fmaf(w6, bflo(u6), ax); ay = fmaf(w6, bfhi(u6), ay);
        ax = fmaf(w7, bflo(u7), ax); ay = fmaf(w7, bfhi(u7), ay);
    }

    float2 bb = ((const float2*)bias)[lane];
    float a0 = fmaxf(fmaf(ax, di, bb.x), 0.f);
    float a1 = fmaxf(fmaf(ay, di, bb.y), 0.f);

    float s1 = a0 + a1;
    float s2 = a0 * a0 + a1 * a1;
#pragma unroll
    for (int off = 32; off >= 1; off >>= 1) {
        s1 += __shfl_xor(s1, off);
        s2 += __shfl_xor(s2, off);
    }
    float mu = s1 * (1.f / 128.f);
    float var = s2 * (1.f / 128.f) - mu * mu;
    float rs = rsqrtf(var + LN_EPS);

    float2 g = ((const float2*)gamma)[lane];
    float2 be = ((const float2*)beta)[lane];
    float o0 = (a0 - mu) * rs * g.x + be.x;
    float o1 = (a1 - mu) * rs * g.y + be.y;
    if (outf) {
        ((float2*)outf)[(size_t)node * 64 + lane] = make_float2(o0, o1);
    } else {
        outb[(size_t)node * 64 + lane] = (uint)f2bf(o0) | ((uint)f2bf(o1) << 16);
    }
}

// ---------------- launch ----------------
extern "C" void kernel_launch(void* const* d_in, const int* in_sizes, int n_in,
                              void* d_out, int out_size, void* d_ws, size_t ws_size,
                              hipStream_t stream) {
    const float* x  = (const float*)d_in[0];
    const int*   ei = (const int*)d_in[1];
    const float* W1 = (const float*)d_in[2];
    const float* b1 = (const float*)d_in[3];
    const float* W2 = (const float*)d_in[4];
    const float* b2 = (const float*)d_in[5];
    const float* g1 = (const float*)d_in[6];
    const float* be1 = (const float*)d_in[7];
    const float* g2 = (const float*)d_in[8];
    const float* be2 = (const float*)d_in[9];

    int N = in_sizes[0] / FDIM;
    int E = in_sizes[1] / 2;
    const int* srcp = ei;
    const int* dstp = ei + E;
    float* out = (float*)d_out;

    char* w = (char*)d_ws;
    size_t off = 0;
    auto take = [&](size_t bytes) {
        void* p = w + off;
        off = (off + bytes + 255) & ~(size_t)255;
        return p;
    };
    ushort* hb   = (ushort*)take((size_t)N * FDIM * sizeof(ushort));   // gemm out bf16
    ushort* WT1  = (ushort*)take(128 * 128 * sizeof(ushort));
    ushort* WT2  = (ushort*)take(128 * 128 * sizeof(ushort));
    int* cnt     = (int*)take((size_t)N * sizeof(int));
    int* rowptr  = (int*)take((size_t)(N + 1) * sizeof(int));
    int* pos     = (int*)take((size_t)E * sizeof(int));
    int* colb    = (int*)take((size_t)(E + 8) * sizeof(int));
    float* dinv  = (float*)take((size_t)N * sizeof(float));
    int* partial = (int*)take(1024 * sizeof(int));
    (void)ws_size;

    int NB = (N + 1023) >> 10;

    // CSR build (shared by both layers)
    k_zero<<<(N + 255) / 256, 256, 0, stream>>>(cnt, N);
    k_count<<<(E + 255) / 256, 256, 0, stream>>>(dstp, cnt, pos, E);
    k_scan_block<<<NB, 1024, 0, stream>>>(cnt, rowptr, partial, N);
    k_scan_partial<<<1, 1024, 0, stream>>>(partial, NB);
    k_finalize<<<(N + 255) / 256, 256, 0, stream>>>(rowptr, partial, cnt, dinv, N, E);
    k_fill<<<(E + 255) / 256, 256, 0, stream>>>(srcp, dstp, rowptr, pos, colb, E);

    // weights -> W^T bf16
    k_wt2<<<256, 128, 0, stream>>>(W1, W2, WT1, WT2);

    // layer 1: gemm (fp32 in, convert fused) -> agg (bf16 out into d_out front)
    k_gemm<true><<<(N + 63) / 64, 256, 0, stream>>>(x, WT1, hb, N);
    k_agg<<<(N + 3) / 4, 256, 0, stream>>>((const uint*)hb, rowptr, colb, dinv,
                                           b1, g1, be1, nullptr, (uint*)d_out, N);
    // layer 2: gemm reads bf16 from d_out, agg writes final fp32 d_out
    k_gemm<false><<<(N + 63) / 64, 256, 0, stream>>>(d_out, WT2, hb, N);
    k_agg<<<(N + 3) / 4, 256, 0, stream>>>((const uint*)hb, rowptr, colb, dinv,
                                           b2, g2, be2, out, nullptr, N);
}